// Round 1
// baseline (626.935 us; speedup 1.0000x reference)
//
#include <hip/hip_runtime.h>

// BNB 8-bit embedding dequant-on-gather.
// out[t, d] = code[q_idx_flat[x[t]*1024 + d]] * absmax[x[t]/64, (x[t]%64)>>2]
//
// Note: blk = (local*1024 + d)//4096 is constant over d in [0,1024) because
// local*1024 is 1024-aligned and the span is exactly 1024 -> blk = local>>2.
// So scale is one scalar per token.

#define EMBED_DIM 1024

__global__ __launch_bounds__(256) void bnb8_embed_kernel(
    const int*   __restrict__ x,
    const int*   __restrict__ q_idx,    // [2000*64*1024] flat
    const float* __restrict__ absmax,   // [2000*16] flat
    const float* __restrict__ code,     // [256]
    float*       __restrict__ out)      // [n_tokens*1024]
{
    __shared__ float code_lds[256];
    const int tid = threadIdx.x;        // 0..255
    code_lds[tid] = code[tid];

    const int token = blockIdx.x;
    const int xv    = x[token];         // same-address broadcast across block
    const int local = xv & 63;
    const int chunk = xv >> 6;
    const float scale = absmax[chunk * 16 + (local >> 2)];
    __syncthreads();

    // Each thread: 16B vector load of 4 code indices, 4 LDS lookups, 16B store.
    const int4 q = ((const int4*)(q_idx + (size_t)xv * EMBED_DIM))[tid];
    float4 v;
    v.x = code_lds[q.x] * scale;
    v.y = code_lds[q.y] * scale;
    v.z = code_lds[q.z] * scale;
    v.w = code_lds[q.w] * scale;
    ((float4*)(out + (size_t)token * EMBED_DIM))[tid] = v;
}

extern "C" void kernel_launch(void* const* d_in, const int* in_sizes, int n_in,
                              void* d_out, int out_size, void* d_ws, size_t ws_size,
                              hipStream_t stream) {
    const int*   x      = (const int*)d_in[0];    // [8*4096]
    const int*   q_idx  = (const int*)d_in[1];    // [2000,64,1024]
    const float* absmax = (const float*)d_in[2];  // [2000,16]
    const float* code   = (const float*)d_in[3];  // [256]
    float*       out    = (float*)d_out;          // [8,4096,1024] fp32

    const int n_tokens = in_sizes[0];             // 32768
    bnb8_embed_kernel<<<n_tokens, 256, 0, stream>>>(x, q_idx, absmax, code, out);
}